// Round 1
// baseline (374.957 us; speedup 1.0000x reference)
//
#include <hip/hip_runtime.h>

#define NH   32
#define NKV  8
#define HD   128
#define QSTRIDE (NH*HD)    // 4096
#define KSTRIDE (NKV*HD)   // 1024
#define SCALE 0.08838834764831845f

typedef __attribute__((ext_vector_type(8))) short short8;
typedef __attribute__((ext_vector_type(4))) float f32x4;

__device__ __forceinline__ unsigned short f2bf(float f) {
    unsigned u = __builtin_bit_cast(unsigned, f);
    unsigned r = u + 0x7fffu + ((u >> 16) & 1u);
    return (unsigned short)(r >> 16);
}

__launch_bounds__(256, 3)
__global__ void attn_fwd(const float* __restrict__ Qg,
                         const float* __restrict__ Kg,
                         const float* __restrict__ Vg,
                         float* __restrict__ Og) {
    const int qb   = blockIdx.x;   // q block: rows [qb*64, qb*64+64)
    const int h    = blockIdx.y;   // query head
    const int hk   = h >> 2;       // kv head (repeat_interleave, G=4)
    const int tid  = threadIdx.x;
    const int w    = tid >> 6;     // wave 0..3
    const int lane = tid & 63;
    const int c16  = lane & 15;
    const int g    = lane >> 4;    // 0..3
    const int dg   = g * 8;        // k-offset group for A/B fragments

    // K tile row-major (pad +8 -> 2-way bank alias, free); V transposed [d][kv]
    __shared__ unsigned short Ks[64][136];
    __shared__ unsigned short Vt[128][72];
    __shared__ unsigned short Ps[4][16][72];   // per-wave P tile

    const int q0w = qb * 64 + w * 16;          // this wave's first q row

    // ---- load Q fragments (A operand: row = lane&15, k = 32*ks + 8*g + i) ----
    short8 qf[4];
    {
        const float* qp = Qg + (size_t)(q0w + c16) * QSTRIDE + h * HD + dg;
        #pragma unroll
        for (int ks = 0; ks < 4; ++ks) {
            float4 a = *(const float4*)(qp + ks * 32);
            float4 b = *(const float4*)(qp + ks * 32 + 4);
            short8 f;
            f[0] = (short)f2bf(a.x); f[1] = (short)f2bf(a.y);
            f[2] = (short)f2bf(a.z); f[3] = (short)f2bf(a.w);
            f[4] = (short)f2bf(b.x); f[5] = (short)f2bf(b.y);
            f[6] = (short)f2bf(b.z); f[7] = (short)f2bf(b.w);
            qf[ks] = f;
        }
    }

    f32x4 oacc[8];
    #pragma unroll
    for (int dt = 0; dt < 8; ++dt) oacc[dt] = (f32x4){0.f, 0.f, 0.f, 0.f};
    float m_r[4], l_r[4];
    #pragma unroll
    for (int r = 0; r < 4; ++r) { m_r[r] = -1e30f; l_r[r] = 0.f; }

    const int ntiles = qb + 1;                 // causal: kv tiles 0..qb
    for (int t = 0; t < ntiles; ++t) {
        const int kv0 = t * 64;
        __syncthreads();   // previous tile's LDS reads complete before overwrite
        // ---- cooperative stage: K row-major, V transposed, fp32 -> bf16 ----
        #pragma unroll
        for (int it = 0; it < 8; ++it) {
            int idx = tid + it * 256;          // 0..2047 over 64 rows x 32 f4-groups
            int row = idx >> 5;
            int cg  = (idx & 31) * 4;
            const float* kp = Kg + (size_t)(kv0 + row) * KSTRIDE + hk * HD + cg;
            const float* vp = Vg + (size_t)(kv0 + row) * KSTRIDE + hk * HD + cg;
            float4 k4 = *(const float4*)kp;
            float4 v4 = *(const float4*)vp;
            ushort4 ku;
            ku.x = f2bf(k4.x); ku.y = f2bf(k4.y);
            ku.z = f2bf(k4.z); ku.w = f2bf(k4.w);
            *(ushort4*)&Ks[row][cg] = ku;
            Vt[cg + 0][row] = f2bf(v4.x);
            Vt[cg + 1][row] = f2bf(v4.y);
            Vt[cg + 2][row] = f2bf(v4.z);
            Vt[cg + 3][row] = f2bf(v4.w);
        }
        __syncthreads();

        // ---- S = Q K^T  (S[q=4g+r][kv=16ct+c16] per D-layout) ----
        f32x4 sacc[4];
        #pragma unroll
        for (int ct = 0; ct < 4; ++ct) {
            f32x4 acc = (f32x4){0.f, 0.f, 0.f, 0.f};
            #pragma unroll
            for (int ks = 0; ks < 4; ++ks) {
                short8 bf = *(const short8*)&Ks[ct * 16 + c16][ks * 32 + dg];
                acc = __builtin_amdgcn_mfma_f32_16x16x32_bf16(qf[ks], bf, acc, 0, 0, 0);
            }
            sacc[ct] = acc;
        }

        // ---- scale + causal mask + row max ----
        float rmax[4];
        #pragma unroll
        for (int r = 0; r < 4; ++r) rmax[r] = -1e30f;
        const bool needmask = (kv0 + 63 > q0w);
        #pragma unroll
        for (int ct = 0; ct < 4; ++ct) {
            const int kk = kv0 + ct * 16 + c16;
            #pragma unroll
            for (int r = 0; r < 4; ++r) {
                float s = sacc[ct][r] * SCALE;
                const int qrow = q0w + 4 * g + r;
                if (needmask && kk > qrow) s = -1e30f;
                sacc[ct][r] = s;
                rmax[r] = fmaxf(rmax[r], s);
            }
        }
        #pragma unroll
        for (int r = 0; r < 4; ++r) {          // reduce over the 16 col-lanes
            float vv = rmax[r];
            vv = fmaxf(vv, __shfl_xor(vv, 1));
            vv = fmaxf(vv, __shfl_xor(vv, 2));
            vv = fmaxf(vv, __shfl_xor(vv, 4));
            vv = fmaxf(vv, __shfl_xor(vv, 8));
            rmax[r] = vv;
        }

        float fac[4], psum[4];
        #pragma unroll
        for (int r = 0; r < 4; ++r) {
            float mn = fmaxf(m_r[r], rmax[r]);
            fac[r]  = __expf(m_r[r] - mn);
            m_r[r]  = mn;
            psum[r] = 0.f;
        }

        // ---- P = exp(S - m): accumulate row sums, spill bf16 P to LDS ----
        #pragma unroll
        for (int ct = 0; ct < 4; ++ct) {
            #pragma unroll
            for (int r = 0; r < 4; ++r) {
                float p = __expf(sacc[ct][r] - m_r[r]);
                psum[r] += p;
                Ps[w][4 * g + r][ct * 16 + c16] = f2bf(p);
            }
        }
        #pragma unroll
        for (int r = 0; r < 4; ++r) {
            float vv = psum[r];
            vv += __shfl_xor(vv, 1);
            vv += __shfl_xor(vv, 2);
            vv += __shfl_xor(vv, 4);
            vv += __shfl_xor(vv, 8);
            l_r[r] = l_r[r] * fac[r] + vv;
        }
        // ---- rescale O ----
        #pragma unroll
        for (int dt = 0; dt < 8; ++dt) {
            #pragma unroll
            for (int r = 0; r < 4; ++r) oacc[dt][r] *= fac[r];
        }

        // wave-local: ensure P ds_writes landed before cross-lane ds_reads
        asm volatile("s_waitcnt lgkmcnt(0)" ::: "memory");
        __builtin_amdgcn_sched_barrier(0);

        // ---- O += P V  (A = P: row=c16, k=32ks+dg; B = Vt[d][kv]) ----
        #pragma unroll
        for (int ks = 0; ks < 2; ++ks) {
            short8 pf = *(const short8*)&Ps[w][c16][ks * 32 + dg];
            #pragma unroll
            for (int dt = 0; dt < 8; ++dt) {
                short8 vf = *(const short8*)&Vt[dt * 16 + c16][ks * 32 + dg];
                oacc[dt] = __builtin_amdgcn_mfma_f32_16x16x32_bf16(pf, vf, oacc[dt], 0, 0, 0);
            }
        }
    }

    // ---- epilogue: normalize and store fp32 ----
    #pragma unroll
    for (int dt = 0; dt < 8; ++dt) {
        #pragma unroll
        for (int r = 0; r < 4; ++r) {
            float o = oacc[dt][r] / l_r[r];
            Og[(size_t)(q0w + 4 * g + r) * QSTRIDE + h * HD + dt * 16 + c16] = o;
        }
    }
}

extern "C" void kernel_launch(void* const* d_in, const int* in_sizes, int n_in,
                              void* d_out, int out_size, void* d_ws, size_t ws_size,
                              hipStream_t stream) {
    const float* q = (const float*)d_in[0];
    const float* k = (const float*)d_in[1];
    const float* v = (const float*)d_in[2];
    float* out = (float*)d_out;
    dim3 grid(32, 32, 1);   // x: q-block, y: head
    attn_fwd<<<grid, 256, 0, stream>>>(q, k, v, out);
}

// Round 2
// 184.931 us; speedup vs baseline: 2.0276x; 2.0276x over previous
//
#include <hip/hip_runtime.h>
#include <hip/hip_bf16.h>

#define QSTRIDE 4096
#define KSTRIDE 1024
// (1/sqrt(128)) * log2(e): fold attn scale + exp->exp2 conversion into Q
#define CSCALE 0.1275174364688796f

typedef __attribute__((ext_vector_type(8))) short short8;
typedef __attribute__((ext_vector_type(4))) float f32x4;

__device__ __forceinline__ unsigned short f2bf(float f) {
    union { __hip_bfloat16 b; unsigned short u; } cv;
    cv.b = __float2bfloat16(f);
    return cv.u;
}

__launch_bounds__(256, 3)
__global__ void attn_fwd(const float* __restrict__ Qg,
                         const float* __restrict__ Kg,
                         const float* __restrict__ Vg,
                         float* __restrict__ Og) {
    const int bid = blockIdx.x;
    const int qb  = 31 - (bid >> 5);   // LPT: longest blocks first
    const int h   = bid & 31;
    const int hk  = h >> 2;
    const int tid  = threadIdx.x;
    const int w    = tid >> 6;
    const int lane = tid & 63;
    const int c16  = lane & 15;
    const int g    = lane >> 4;
    const int dg   = g * 8;

    __shared__ unsigned short Ks[64][136];   // [kv][d], row-major
    __shared__ unsigned short Vt[128][72];   // [d][kv'], kv' = 4*(kv&15)+(kv>>4)
    __shared__ unsigned short Ps[4][16][72]; // per-wave P, col = kv'

    const int q0w = qb * 64 + w * 16;

    // ---- Q fragments with folded scale ----
    short8 qf[4];
    {
        const float* qp = Qg + (size_t)(q0w + c16) * QSTRIDE + h * 128 + dg;
        #pragma unroll
        for (int ks = 0; ks < 4; ++ks) {
            float4 a = *(const float4*)(qp + ks * 32);
            float4 b = *(const float4*)(qp + ks * 32 + 4);
            short8 f;
            f[0] = (short)f2bf(a.x * CSCALE); f[1] = (short)f2bf(a.y * CSCALE);
            f[2] = (short)f2bf(a.z * CSCALE); f[3] = (short)f2bf(a.w * CSCALE);
            f[4] = (short)f2bf(b.x * CSCALE); f[5] = (short)f2bf(b.y * CSCALE);
            f[6] = (short)f2bf(b.z * CSCALE); f[7] = (short)f2bf(b.w * CSCALE);
            qf[ks] = f;
        }
    }

    // staging decode constants
    const int ka  = tid >> 5;         // K row base (+8 per it)
    const int kc  = (tid & 31) * 4;   // K d offset
    const int vr0 = tid & 15;         // V kv base (rows r0+16j)
    const int vc  = tid >> 4;         // V d-chunk base (+16 per task)

    float4 kreg[8];
    float4 vreg[8];

    auto LOAD = [&](int t) {
        const float* kb = Kg + (size_t)(t * 64) * KSTRIDE + hk * 128;
        const float* vb = Vg + (size_t)(t * 64) * KSTRIDE + hk * 128;
        #pragma unroll
        for (int it = 0; it < 8; ++it)
            kreg[it] = *(const float4*)(kb + (ka + 8 * it) * KSTRIDE + kc);
        #pragma unroll
        for (int task = 0; task < 2; ++task) {
            const float* vp = vb + (size_t)vr0 * KSTRIDE + (vc + 16 * task) * 4;
            #pragma unroll
            for (int j = 0; j < 4; ++j)
                vreg[task * 4 + j] = *(const float4*)(vp + j * 16 * KSTRIDE);
        }
    };

    auto WRITE = [&]() {
        #pragma unroll
        for (int it = 0; it < 8; ++it) {
            ushort4 u = make_ushort4(f2bf(kreg[it].x), f2bf(kreg[it].y),
                                     f2bf(kreg[it].z), f2bf(kreg[it].w));
            *(ushort4*)&Ks[ka + 8 * it][kc] = u;
        }
        #pragma unroll
        for (int task = 0; task < 2; ++task) {
            const int d0 = (vc + 16 * task) * 4;
            float4 v0 = vreg[task * 4 + 0], v1 = vreg[task * 4 + 1];
            float4 v2 = vreg[task * 4 + 2], v3 = vreg[task * 4 + 3];
            ushort4 u;
            u = make_ushort4(f2bf(v0.x), f2bf(v1.x), f2bf(v2.x), f2bf(v3.x));
            *(ushort4*)&Vt[d0 + 0][4 * vr0] = u;
            u = make_ushort4(f2bf(v0.y), f2bf(v1.y), f2bf(v2.y), f2bf(v3.y));
            *(ushort4*)&Vt[d0 + 1][4 * vr0] = u;
            u = make_ushort4(f2bf(v0.z), f2bf(v1.z), f2bf(v2.z), f2bf(v3.z));
            *(ushort4*)&Vt[d0 + 2][4 * vr0] = u;
            u = make_ushort4(f2bf(v0.w), f2bf(v1.w), f2bf(v2.w), f2bf(v3.w));
            *(ushort4*)&Vt[d0 + 3][4 * vr0] = u;
        }
    };

    f32x4 oacc[8];
    #pragma unroll
    for (int dt = 0; dt < 8; ++dt) oacc[dt] = (f32x4){0.f, 0.f, 0.f, 0.f};
    float m_r[4], l_r[4];
    #pragma unroll
    for (int r = 0; r < 4; ++r) { m_r[r] = -1e30f; l_r[r] = 0.f; }

    const int nt = qb + 1;
    LOAD(0);
    WRITE();                       // implicit vmcnt waits on reg use
    if (nt > 1) LOAD(1);
    __syncthreads();

    for (int t = 0; t < nt; ++t) {
        const int kv0 = t * 64;

        // ---- S = Q K^T (scaled, log2 units) ----
        f32x4 sacc[4];
        __builtin_amdgcn_s_setprio(1);
        #pragma unroll
        for (int ct = 0; ct < 4; ++ct) {
            f32x4 acc = (f32x4){0.f, 0.f, 0.f, 0.f};
            #pragma unroll
            for (int ks = 0; ks < 4; ++ks) {
                short8 bf = *(const short8*)&Ks[ct * 16 + c16][ks * 32 + dg];
                acc = __builtin_amdgcn_mfma_f32_16x16x32_bf16(qf[ks], bf, acc, 0, 0, 0);
            }
            sacc[ct] = acc;
        }
        __builtin_amdgcn_s_setprio(0);

        // ---- mask + row max ----
        float rmax[4];
        #pragma unroll
        for (int r = 0; r < 4; ++r) rmax[r] = -1e30f;
        const bool needmask = (kv0 + 63 > q0w);
        #pragma unroll
        for (int ct = 0; ct < 4; ++ct) {
            const int kk = kv0 + ct * 16 + c16;
            #pragma unroll
            for (int r = 0; r < 4; ++r) {
                float s = sacc[ct][r];
                const int qrow = q0w + 4 * g + r;
                if (needmask && kk > qrow) s = -1e30f;
                sacc[ct][r] = s;
                rmax[r] = fmaxf(rmax[r], s);
            }
        }
        #pragma unroll
        for (int r = 0; r < 4; ++r) {
            float vv = rmax[r];
            vv = fmaxf(vv, __shfl_xor(vv, 1));
            vv = fmaxf(vv, __shfl_xor(vv, 2));
            vv = fmaxf(vv, __shfl_xor(vv, 4));
            vv = fmaxf(vv, __shfl_xor(vv, 8));
            rmax[r] = vv;
        }

        float fac[4], psum[4];
        #pragma unroll
        for (int r = 0; r < 4; ++r) {
            float mn = fmaxf(m_r[r], rmax[r]);
            fac[r]  = exp2f(m_r[r] - mn);
            m_r[r]  = mn;
            psum[r] = 0.f;
        }

        // ---- P = 2^(S-m); write to Ps at permuted col kv' = 4*c16 + ct ----
        #pragma unroll
        for (int ct = 0; ct < 4; ++ct) {
            #pragma unroll
            for (int r = 0; r < 4; ++r) {
                float p = exp2f(sacc[ct][r] - m_r[r]);
                psum[r] += p;
                Ps[w][4 * g + r][4 * c16 + ct] = f2bf(p);
            }
        }
        #pragma unroll
        for (int r = 0; r < 4; ++r) {
            float vv = psum[r];
            vv += __shfl_xor(vv, 1);
            vv += __shfl_xor(vv, 2);
            vv += __shfl_xor(vv, 4);
            vv += __shfl_xor(vv, 8);
            l_r[r] = l_r[r] * fac[r] + vv;
        }
        #pragma unroll
        for (int dt = 0; dt < 8; ++dt) {
            #pragma unroll
            for (int r = 0; r < 4; ++r) oacc[dt][r] *= fac[r];
        }

        // wave-local: P ds_writes must land before cross-lane reads (rule 18)
        asm volatile("s_waitcnt lgkmcnt(0)" ::: "memory");
        __builtin_amdgcn_sched_barrier(0);

        // ---- O += P V (k enumerated in kv' order on both operands) ----
        __builtin_amdgcn_s_setprio(1);
        #pragma unroll
        for (int ks = 0; ks < 2; ++ks) {
            short8 pf = *(const short8*)&Ps[w][c16][ks * 32 + dg];
            #pragma unroll
            for (int dt = 0; dt < 8; ++dt) {
                short8 vf = *(const short8*)&Vt[dt * 16 + c16][ks * 32 + dg];
                oacc[dt] = __builtin_amdgcn_mfma_f32_16x16x32_bf16(pf, vf, oacc[dt], 0, 0, 0);
            }
        }
        __builtin_amdgcn_s_setprio(0);

        // ---- async staging of tile t+1 (regs already in flight) ----
        if (t + 1 < nt) {
            __syncthreads();           // all waves done reading tile t
            WRITE();                   // cvt + ds_write tile t+1
            if (t + 2 < nt) LOAD(t + 2);
            __syncthreads();           // tile t+1 ready
        }
    }

    // ---- epilogue ----
    #pragma unroll
    for (int dt = 0; dt < 8; ++dt) {
        #pragma unroll
        for (int r = 0; r < 4; ++r) {
            float o = oacc[dt][r] / l_r[r];
            Og[(size_t)(q0w + 4 * g + r) * QSTRIDE + h * 128 + dt * 16 + c16] = o;
        }
    }
}

extern "C" void kernel_launch(void* const* d_in, const int* in_sizes, int n_in,
                              void* d_out, int out_size, void* d_ws, size_t ws_size,
                              hipStream_t stream) {
    const float* q = (const float*)d_in[0];
    const float* k = (const float*)d_in[1];
    const float* v = (const float*)d_in[2];
    float* out = (float*)d_out;
    attn_fwd<<<dim3(1024), 256, 0, stream>>>(q, k, v, out);
}

// Round 3
// 104.097 us; speedup vs baseline: 3.6020x; 1.7765x over previous
//
#include <hip/hip_runtime.h>
#include <hip/hip_bf16.h>

#define QSTRIDE 4096
#define KSTRIDE 1024
// (1/sqrt(128)) * log2(e): fold attn scale + exp->exp2 into Q
#define CSCALE 0.1275174364688796f

typedef __attribute__((ext_vector_type(8))) short short8;
typedef __attribute__((ext_vector_type(4))) float f32x4;

union S8U { short8 s; unsigned u[4]; };

__device__ __forceinline__ unsigned short f2bf(float f) {
    union { __hip_bfloat16 b; unsigned short u; } cv;
    cv.b = __float2bfloat16(f);
    return cv.u;
}

__launch_bounds__(256, 3)
__global__ void attn_fwd(const float* __restrict__ Qg,
                         const float* __restrict__ Kg,
                         const float* __restrict__ Vg,
                         float* __restrict__ Og) {
    const int bid = blockIdx.x;
    const int qb  = 31 - (bid >> 5);   // LPT: longest blocks first
    const int h   = bid & 31;
    const int hk  = h >> 2;
    const int tid  = threadIdx.x;
    const int w    = tid >> 6;
    const int lane = tid & 63;
    const int c16  = lane & 15;
    const int g    = lane >> 4;
    const int dg   = g * 8;

    __shared__ unsigned short Ks[64][136];   // [kv][d] row-major
    __shared__ unsigned short Vt[128][72];   // [d][kv]  (true V^T, unpermuted)

    const int q0w  = qb * 64 + w * 16;
    const int qrow = q0w + c16;              // this lane's softmax q-row

    // ---- Q fragment (B operand: col=c16=q, k = 32ks+8g+i), scale folded ----
    short8 qf[4];
    {
        const float* qp = Qg + (size_t)qrow * QSTRIDE + h * 128 + dg;
        #pragma unroll
        for (int ks = 0; ks < 4; ++ks) {
            f32x4 a = *(const f32x4*)(qp + ks * 32);
            f32x4 b = *(const f32x4*)(qp + ks * 32 + 4);
            short8 f;
            f[0] = (short)f2bf(a[0] * CSCALE); f[1] = (short)f2bf(a[1] * CSCALE);
            f[2] = (short)f2bf(a[2] * CSCALE); f[3] = (short)f2bf(a[3] * CSCALE);
            f[4] = (short)f2bf(b[0] * CSCALE); f[5] = (short)f2bf(b[1] * CSCALE);
            f[6] = (short)f2bf(b[2] * CSCALE); f[7] = (short)f2bf(b[3] * CSCALE);
            qf[ks] = f;
        }
    }

    // staging decode
    const int ka  = tid >> 5;          // K row base (+8 per it)
    const int kc  = (tid & 31) * 4;    // K d offset
    const int va  = tid & 15;          // V kv group: rows 4*va+j
    const int vch = tid >> 4;          // V d-chunk (task0: vch, task1: vch+16)

    f32x4 kreg[8], vreg[8];

    auto LOAD_T = [&](int t) {
        const float* kb = Kg + (size_t)(t * 64) * KSTRIDE + hk * 128;
        const float* vb = Vg + (size_t)(t * 64) * KSTRIDE + hk * 128;
        #pragma unroll
        for (int it = 0; it < 8; ++it)
            kreg[it] = *(const f32x4*)(kb + (ka + 8 * it) * KSTRIDE + kc);
        #pragma unroll
        for (int task = 0; task < 2; ++task) {
            #pragma unroll
            for (int j = 0; j < 4; ++j)
                vreg[task * 4 + j] =
                    *(const f32x4*)(vb + (4 * va + j) * KSTRIDE + (vch + 16 * task) * 4);
        }
    };

    auto WRITE_T = [&]() {
        #pragma unroll
        for (int it = 0; it < 8; ++it) {
            ushort4 u = make_ushort4(f2bf(kreg[it][0]), f2bf(kreg[it][1]),
                                     f2bf(kreg[it][2]), f2bf(kreg[it][3]));
            *(ushort4*)&Ks[ka + 8 * it][kc] = u;
        }
        #pragma unroll
        for (int task = 0; task < 2; ++task) {
            const int d0 = 4 * (vch + 16 * task);
            #pragma unroll
            for (int di = 0; di < 4; ++di) {
                ushort4 u = make_ushort4(f2bf(vreg[task * 4 + 0][di]),
                                         f2bf(vreg[task * 4 + 1][di]),
                                         f2bf(vreg[task * 4 + 2][di]),
                                         f2bf(vreg[task * 4 + 3][di]));
                *(ushort4*)&Vt[d0 + di][4 * va] = u;   // 16 lanes, stride 2 dwords: conflict-free
            }
        }
    };

    f32x4 oacc[8];
    #pragma unroll
    for (int dt = 0; dt < 8; ++dt) oacc[dt] = (f32x4){0.f, 0.f, 0.f, 0.f};
    float m = -1e30f, l = 0.f;

    const int nt = qb + 1;
    LOAD_T(0);
    WRITE_T();
    if (nt > 1) LOAD_T(1);
    __syncthreads();

    for (int t = 0; t < nt; ++t) {
        const int kv0 = t * 64;

        // ---- S^T = K Q^T : lane holds S[kv=16ct+4g+r][q=c16] ----
        f32x4 sacc[4];
        __builtin_amdgcn_s_setprio(1);
        #pragma unroll
        for (int ct = 0; ct < 4; ++ct) {
            f32x4 acc = (f32x4){0.f, 0.f, 0.f, 0.f};
            #pragma unroll
            for (int ks = 0; ks < 4; ++ks) {
                short8 kf = *(const short8*)&Ks[ct * 16 + c16][ks * 32 + dg];
                acc = __builtin_amdgcn_mfma_f32_16x16x32_bf16(kf, qf[ks], acc, 0, 0, 0);
            }
            sacc[ct] = acc;
        }
        __builtin_amdgcn_s_setprio(0);

        // ---- mask + in-lane max ----
        const bool needmask = (kv0 + 63) > q0w;
        float mx = -1e30f;
        #pragma unroll
        for (int ct = 0; ct < 4; ++ct) {
            #pragma unroll
            for (int r = 0; r < 4; ++r) {
                float s = sacc[ct][r];
                const int kv = kv0 + ct * 16 + 4 * g + r;
                if (needmask && kv > qrow) s = -1e30f;
                sacc[ct][r] = s;
                mx = fmaxf(mx, s);
            }
        }
        mx = fmaxf(mx, __shfl_xor(mx, 16));
        mx = fmaxf(mx, __shfl_xor(mx, 32));

        const float mn  = fmaxf(m, mx);
        const float fac = exp2f(m - mn);
        m = mn;

        // ---- P = 2^(S-m), in-lane sum ----
        float ps = 0.f;
        #pragma unroll
        for (int ct = 0; ct < 4; ++ct) {
            #pragma unroll
            for (int r = 0; r < 4; ++r) {
                float p = exp2f(sacc[ct][r] - m);
                sacc[ct][r] = p;
                ps += p;
            }
        }
        ps += __shfl_xor(ps, 16);
        ps += __shfl_xor(ps, 32);
        l = l * fac + ps;

        #pragma unroll
        for (int dt = 0; dt < 8; ++dt) {
            #pragma unroll
            for (int r = 0; r < 4; ++r) oacc[dt][r] *= fac;
        }

        // ---- pack P to bf16 pairs, redistribute in-register to B-fragments ----
        // pk[ct][j] = (p[ct][2j], p[ct][2j+1]) as bf16x2
        unsigned pk[4][2];
        #pragma unroll
        for (int ct = 0; ct < 4; ++ct) {
            #pragma unroll
            for (int j = 0; j < 2; ++j)
                pk[ct][j] = (unsigned)f2bf(sacc[ct][2 * j]) |
                            ((unsigned)f2bf(sacc[ct][2 * j + 1]) << 16);
        }
        // target lane (c16,g) needs pk[2ks+(g>>1)][j] from src lane 16*(2(g&1)+b)+c16
        S8U pf0, pf1;
        {
            const int sb = ((g & 1) << 5) | c16;
            #pragma unroll
            for (int b = 0; b < 2; ++b) {
                const int src = sb + (b << 4);
                #pragma unroll
                for (int j = 0; j < 2; ++j) {
                    unsigned lo0 = (unsigned)__shfl((int)pk[0][j], src);
                    unsigned hi0 = (unsigned)__shfl((int)pk[1][j], src);
                    unsigned lo1 = (unsigned)__shfl((int)pk[2][j], src);
                    unsigned hi1 = (unsigned)__shfl((int)pk[3][j], src);
                    pf0.u[2 * b + j] = (g & 2) ? hi0 : lo0;
                    pf1.u[2 * b + j] = (g & 2) ? hi1 : lo1;
                }
            }
        }

        // ---- O^T += V^T P : lane holds O[q=c16][d=16dt+4g+r] ----
        __builtin_amdgcn_s_setprio(1);
        #pragma unroll
        for (int dt = 0; dt < 8; ++dt) {
            short8 vfa = *(const short8*)&Vt[dt * 16 + c16][0 * 32 + dg];
            short8 vfb = *(const short8*)&Vt[dt * 16 + c16][1 * 32 + dg];
            oacc[dt] = __builtin_amdgcn_mfma_f32_16x16x32_bf16(vfa, pf0.s, oacc[dt], 0, 0, 0);
            oacc[dt] = __builtin_amdgcn_mfma_f32_16x16x32_bf16(vfb, pf1.s, oacc[dt], 0, 0, 0);
        }
        __builtin_amdgcn_s_setprio(0);

        // ---- async staging of tile t+1 ----
        if (t + 1 < nt) {
            __syncthreads();
            WRITE_T();
            if (t + 2 < nt) LOAD_T(t + 2);
            __syncthreads();
        }
    }

    // ---- epilogue: O[q][d], float4 stores ----
    const float rl = 1.0f / l;
    float* op = Og + (size_t)qrow * QSTRIDE + h * 128 + 4 * g;
    #pragma unroll
    for (int dt = 0; dt < 8; ++dt) {
        float4 o;
        o.x = oacc[dt][0] * rl; o.y = oacc[dt][1] * rl;
        o.z = oacc[dt][2] * rl; o.w = oacc[dt][3] * rl;
        *(float4*)(op + dt * 16) = o;
    }
}

extern "C" void kernel_launch(void* const* d_in, const int* in_sizes, int n_in,
                              void* d_out, int out_size, void* d_ws, size_t ws_size,
                              hipStream_t stream) {
    const float* q = (const float*)d_in[0];
    const float* k = (const float*)d_in[1];
    const float* v = (const float*)d_in[2];
    float* out = (float*)d_out;
    attn_fwd<<<dim3(1024), 256, 0, stream>>>(q, k, v, out);
}

// Round 5
// 89.368 us; speedup vs baseline: 4.1956x; 1.1648x over previous
//
#include <hip/hip_runtime.h>
#include <hip/hip_bf16.h>

#define SEQ 2048
#define QSTR 4096
#define KSTR 1024
// (1/sqrt(128)) * log2(e)
#define CSCALE 0.1275174364688796f

typedef __attribute__((ext_vector_type(8)))  short short8;
typedef __attribute__((ext_vector_type(4)))  float f32x4;
typedef __attribute__((ext_vector_type(16))) float f32x16;

union PF8 { unsigned u[4]; short8 s; };

__device__ __forceinline__ unsigned short f2bf(float f) {
    union { __hip_bfloat16 b; unsigned short u; } cv;
    cv.b = __float2bfloat16(f);
    return cv.u;
}

__device__ __forceinline__ void gload16(const unsigned short* g, unsigned short* l) {
    __builtin_amdgcn_global_load_lds(
        (const __attribute__((address_space(1))) void*)g,
        (__attribute__((address_space(3))) void*)l, 16, 0, 0);
}

// ---- prepass: K -> bf16 [hk][kv][d] ----
__global__ void prep_k(const float* __restrict__ Kg, unsigned short* __restrict__ Kb) {
    int gi = blockIdx.x * 256 + threadIdx.x;      // 524288 float4 chunks
    int kv = gi >> 8;
    int rem = gi & 255;
    int hk = rem >> 5;
    int d4 = rem & 31;
    f32x4 k4 = *(const f32x4*)(Kg + ((size_t)kv * 8 + hk) * 128 + 4 * d4);
    ushort4 u = make_ushort4(f2bf(k4[0]), f2bf(k4[1]), f2bf(k4[2]), f2bf(k4[3]));
    *(ushort4*)(Kb + ((size_t)hk * SEQ + kv) * 128 + 4 * d4) = u;
}

// ---- prepass: V -> bf16 transposed [hk][d][kv] ----
__global__ void prep_v(const float* __restrict__ Vg, unsigned short* __restrict__ Vtb) {
    const int hk  = blockIdx.x >> 5;
    const int kvb = blockIdx.x & 31;              // kv0 = kvb*64
    __shared__ unsigned short T[128][72];
    const int t = threadIdx.x;
    #pragma unroll
    for (int i = 0; i < 8; ++i) {
        int idx = t + 256 * i;                    // 2048 f4 chunks: r=idx>>5, d4=idx&31
        int r = idx >> 5, d4 = idx & 31;
        f32x4 v = *(const f32x4*)(Vg + ((size_t)(kvb * 64 + r) * 8 + hk) * 128 + 4 * d4);
        T[4 * d4 + 0][r] = f2bf(v[0]);
        T[4 * d4 + 1][r] = f2bf(v[1]);
        T[4 * d4 + 2][r] = f2bf(v[2]);
        T[4 * d4 + 3][r] = f2bf(v[3]);
    }
    __syncthreads();
    #pragma unroll
    for (int i = 0; i < 8; ++i) {
        int idx = t + 256 * i;                    // 2048 ushort4 chunks: d=idx>>4, c4=idx&15
        int d = idx >> 4, c4 = idx & 15;
        ushort4 u = *(ushort4*)&T[d][4 * c4];
        *(ushort4*)(Vtb + ((size_t)hk * 128 + d) * SEQ + kvb * 64 + 4 * c4) = u;
    }
}

__launch_bounds__(256, 2)
__global__ void attn_fwd(const float* __restrict__ Qg,
                         const unsigned short* __restrict__ Kb,
                         const unsigned short* __restrict__ Vtb,
                         float* __restrict__ Og) {
    const int bid  = blockIdx.x;
    const int gidx = bid >> 5;
    const int qb   = (gidx < 8) ? (15 - gidx) : (gidx - 8);  // pairs j & 15-j per CU
    const int h    = bid & 31;
    const int hk   = h >> 2;
    const int tid  = threadIdx.x;
    const int w    = tid >> 6;
    const int lane = tid & 63;
    const int q5   = lane & 31;
    const int t5   = lane >> 5;
    const int swz  = lane & 7;

    __shared__ __align__(16) unsigned char smem[67584];
    typedef unsigned short KsT[64][128];
    typedef unsigned short VtT[128][64];
    KsT* Ks = (KsT*)smem;                       // Ks[0..1][64][128]
    VtT* Vt = (VtT*)(smem + 32768);             // Vt[0..1][128][64]
    float (*Ot)[132] = (float(*)[132])smem;     // epilogue union

    const int q0w = qb * 128 + 32 * w;          // wave's first q row
    const int nt  = 2 * qb + 2;

    // ---- Q fragments (B operand: col=q5, k=8*t5+e), scale folded ----
    short8 qf[8];
    {
        const float* qp = Qg + (size_t)(q0w + q5) * QSTR + h * 128 + 8 * t5;
        #pragma unroll
        for (int st = 0; st < 8; ++st) {
            f32x4 a = *(const f32x4*)(qp + 16 * st);
            f32x4 b = *(const f32x4*)(qp + 16 * st + 4);
            short8 f;
            f[0] = (short)f2bf(a[0] * CSCALE); f[1] = (short)f2bf(a[1] * CSCALE);
            f[2] = (short)f2bf(a[2] * CSCALE); f[3] = (short)f2bf(a[3] * CSCALE);
            f[4] = (short)f2bf(b[0] * CSCALE); f[5] = (short)f2bf(b[1] * CSCALE);
            f[6] = (short)f2bf(b[2] * CSCALE); f[7] = (short)f2bf(b[3] * CSCALE);
            qf[st] = f;
        }
    }
    // force Q loads/converts to complete so the vmcnt pipeline below is clean
    #pragma unroll
    for (int st = 0; st < 8; ++st) asm volatile("" :: "v"(qf[st]));
    asm volatile("s_waitcnt vmcnt(0)" ::: "memory");

    f32x16 oacc[4];
    #pragma unroll
    for (int dt = 0; dt < 4; ++dt)
        #pragma unroll
        for (int r = 0; r < 16; ++r) oacc[dt][r] = 0.f;
    float m = -1e30f, l = 0.f;

    // staging: wave w -> K rows 16w..16w+15 (4 instr), V rows 32w..32w+31 (4 instr)
    auto ISSUE = [&](int t, int b) {
        const int kv0 = t * 64;
        #pragma unroll
        for (int p = 0; p < 4; ++p) {
            int row = 16 * w + 4 * p + (lane >> 4);
            const unsigned short* g = Kb +
                ((size_t)hk * SEQ + kv0 + row) * 128 + 8 * ((lane & 15) ^ (row & 7));
            gload16(g, &Ks[b][16 * w + 4 * p][0]);
        }
        #pragma unroll
        for (int p = 0; p < 4; ++p) {
            int d = 32 * w + 8 * p + (lane >> 3);
            const unsigned short* g = Vtb +
                ((size_t)hk * 128 + d) * SEQ + kv0 + 8 * ((lane & 7) ^ (d & 7));
            gload16(g, &Vt[b][32 * w + 8 * p][0]);
        }
    };

    ISSUE(0, 0);
    if (nt > 1) ISSUE(1, 1);

    for (int t = 0; t < nt; ++t) {
        const int kv0 = t * 64;
        const int buf = t & 1;
        if (t + 1 < nt) asm volatile("s_waitcnt vmcnt(8)" ::: "memory");
        else            asm volatile("s_waitcnt vmcnt(0)" ::: "memory");
        __builtin_amdgcn_s_barrier();   // tile t staged everywhere; buf^1 free

        const bool active = (kv0 <= q0w + 31);
        if (active) {
            // ---- S^T = K Q^T : D[row=kv][col=q5] ----
            f32x16 sac[2];
            __builtin_amdgcn_s_setprio(1);
            #pragma unroll
            for (int kvs = 0; kvs < 2; ++kvs) {
                f32x16 acc;
                #pragma unroll
                for (int r = 0; r < 16; ++r) acc[r] = 0.f;
                #pragma unroll
                for (int st = 0; st < 8; ++st) {
                    short8 kf = *(const short8*)
                        &Ks[buf][32 * kvs + q5][8 * ((2 * st + t5) ^ swz)];
                    acc = __builtin_amdgcn_mfma_f32_32x32x16_bf16(kf, qf[st], acc, 0, 0, 0);
                }
                sac[kvs] = acc;
            }
            __builtin_amdgcn_s_setprio(0);

            // ---- mask (diagonal tiles only) ----
            if (kv0 + 63 > q0w) {
                const int qrow = q0w + q5;
                #pragma unroll
                for (int kvs = 0; kvs < 2; ++kvs)
                    #pragma unroll
                    for (int r = 0; r < 16; ++r) {
                        int kv = kv0 + 32 * kvs + (r & 3) + 8 * (r >> 2) + 4 * t5;
                        if (kv > qrow) sac[kvs][r] = -1e30f;
                    }
            }

            // ---- row max (one cross-lane op) ----
            float mx = sac[0][0];
            #pragma unroll
            for (int kvs = 0; kvs < 2; ++kvs)
                #pragma unroll
                for (int r = 0; r < 16; ++r) mx = fmaxf(mx, sac[kvs][r]);
            mx = fmaxf(mx, __shfl_xor(mx, 32));

            // ---- defer-max (T13): skip O-rescale when growth small ----
            const bool skip = __all(mx <= m + 11.0f);
            float fac = 1.0f;
            if (!skip) {
                float mn = fmaxf(m, mx);
                fac = exp2f(m - mn);
                m = mn;
            }

            float ps = 0.f;
            #pragma unroll
            for (int kvs = 0; kvs < 2; ++kvs)
                #pragma unroll
                for (int r = 0; r < 16; ++r) {
                    float p = exp2f(sac[kvs][r] - m);
                    sac[kvs][r] = p;
                    ps += p;
                }
            ps += __shfl_xor(ps, 32);
            if (!skip) {
                l = l * fac + ps;
                #pragma unroll
                for (int dt = 0; dt < 4; ++dt)
                    #pragma unroll
                    for (int r = 0; r < 16; ++r) oacc[dt][r] *= fac;
            } else {
                l += ps;
            }

            // ---- pack P pairs to bf16x2 ----
            unsigned pkw[2][8];
            #pragma unroll
            for (int a = 0; a < 2; ++a)
                #pragma unroll
                for (int rp = 0; rp < 8; ++rp)
                    pkw[a][rp] = (unsigned)f2bf(sac[a][2 * rp]) |
                                 ((unsigned)f2bf(sac[a][2 * rp + 1]) << 16);

            // ---- redistribute to PV B-fragments ----
            // Needed: pf[ks] elem e = P[kv=16ks+8*t5+e][q5], held by lane
            // (q5, srcT5=e>>2) at pkw[ks>>1][(j&1)+2*t5+4*(ks&1)]. Source is
            // always the same q5 -> only cross-half movement. Use shfl_xor(32)
            // with COMPILE-TIME register indices; select own/partner by t5.
            unsigned xp[2][8];
            #pragma unroll
            for (int a = 0; a < 2; ++a)
                #pragma unroll
                for (int i = 0; i < 8; ++i)
                    xp[a][i] = (unsigned)__shfl_xor((int)pkw[a][i], 32);

            PF8 pf[4];
            #pragma unroll
            for (int ks = 0; ks < 4; ++ks) {
                const int a = ks >> 1;
                #pragma unroll
                for (int j = 0; j < 4; ++j) {
                    const int ib = (j & 1) + 4 * (ks & 1);   // idx for t5=0
                    const unsigned own_lo = pkw[a][ib];
                    const unsigned own_hi = pkw[a][ib + 2];  // idx for t5=1
                    const unsigned par_lo = xp[a][ib];
                    const unsigned par_hi = xp[a][ib + 2];
                    // j<2: source half 0 -> own if t5==0 else partner (hi idx)
                    // j>=2: source half 1 -> partner if t5==0 else own (hi idx)
                    pf[ks].u[j] = (j < 2) ? (t5 ? par_hi : own_lo)
                                          : (t5 ? own_hi : par_lo);
                }
            }

            // ---- O^T += V^T P ----
            __builtin_amdgcn_s_setprio(1);
            #pragma unroll
            for (int dt = 0; dt < 4; ++dt) {
                #pragma unroll
                for (int ks = 0; ks < 4; ++ks) {
                    short8 vf = *(const short8*)
                        &Vt[buf][32 * dt + q5][8 * ((2 * ks + t5) ^ swz)];
                    oacc[dt] = __builtin_amdgcn_mfma_f32_32x32x16_bf16(vf, pf[ks].s, oacc[dt], 0, 0, 0);
                }
            }
            __builtin_amdgcn_s_setprio(0);
        }

        asm volatile("" ::: "memory");
        __builtin_amdgcn_s_barrier();           // all waves done reading buf
        if (t + 2 < nt) ISSUE(t + 2, buf);      // flies across compute(t+1)
    }

    // ---- epilogue: transpose O^T through LDS, coalesced fp32 stores ----
    asm volatile("" ::: "memory");
    const float rl = 1.0f / l;
    #pragma unroll
    for (int dt = 0; dt < 4; ++dt)
        #pragma unroll
        for (int b = 0; b < 4; ++b) {
            f32x4 v;
            v[0] = oacc[dt][4 * b + 0] * rl;
            v[1] = oacc[dt][4 * b + 1] * rl;
            v[2] = oacc[dt][4 * b + 2] * rl;
            v[3] = oacc[dt][4 * b + 3] * rl;
            *(f32x4*)&Ot[32 * w + q5][32 * dt + 8 * b + 4 * t5] = v;
        }
    __syncthreads();
    {
        const int col4 = (tid & 31) * 4;
        const int r0   = tid >> 5;
        float* ob = Og + (size_t)(qb * 128) * QSTR + h * 128;
        #pragma unroll
        for (int i = 0; i < 16; ++i) {
            int row = 8 * i + r0;
            f32x4 v = *(const f32x4*)&Ot[row][col4];
            *(f32x4*)(ob + (size_t)row * QSTR + col4) = v;
        }
    }
}

extern "C" void kernel_launch(void* const* d_in, const int* in_sizes, int n_in,
                              void* d_out, int out_size, void* d_ws, size_t ws_size,
                              hipStream_t stream) {
    const float* q = (const float*)d_in[0];
    const float* k = (const float*)d_in[1];
    const float* v = (const float*)d_in[2];
    float* out = (float*)d_out;
    unsigned short* Kb  = (unsigned short*)d_ws;                 // 8*2048*128 bf16 = 4 MB
    unsigned short* Vtb = Kb + (size_t)8 * SEQ * 128;            // 4 MB
    prep_k<<<dim3(2048), 256, 0, stream>>>(k, Kb);
    prep_v<<<dim3(256), 256, 0, stream>>>(v, Vtb);
    attn_fwd<<<dim3(512), 256, 0, stream>>>(q, Kb, Vtb, out);
}